// Round 10
// baseline (235.637 us; speedup 1.0000x reference)
//
#include <hip/hip_runtime.h>
#include <hip/hip_fp16.h>

// B=64, N=64, D=128, L=4, T=10. Float tensors may arrive as bf16 OR fp32.
// r21: TRUE occupancy unlock. r20b counters: VALUBusy 31%, Mfma 7%, HBM 2.5%
// -> no pipe saturated; latency-bound. r19 was doubly capped at 16 waves/CU:
// VGPR=72 (>64 quantization cliff, m69) AND LDS 58KB @512thr (2 blk x 8 w).
// Fix: 1024-thread blocks (16 waves) x 512 blocks = 2 blocks/CU sharing one
// ew2 slab; __launch_bounds__(1024, 8) forces VGPR<=64 -> 32 waves/CU.
// Wave owns (i = w>>1, cc-half = w&1): per-wave serial work halved, math
// identical to r19 (proven 203us). Node: waves 0-7 only, af2 split into two
// 4-frag passes to stay under the register bound.

typedef _Float16 f16;
typedef _Float16 f16x8 __attribute__((ext_vector_type(8)));
typedef float f32x4 __attribute__((ext_vector_type(4)));

union H2x4 { f16x8 v; __half2 h[4]; };

__device__ __forceinline__ float bf2f(unsigned short u) {
    union { unsigned int i; float f; } v; v.i = ((unsigned int)u) << 16; return v.f;
}
__device__ __forceinline__ unsigned short f2bf(float f) {
    union { float f; unsigned int i; } v; v.f = f;
    unsigned int x = v.i;
    return (unsigned short)((x + 0x7fffu + ((x >> 16) & 1u)) >> 16);
}
__device__ __forceinline__ float silu_f(float x) {
    float e = __builtin_amdgcn_exp2f(-1.44269504088896f * x);
    return x * __builtin_amdgcn_rcpf(1.0f + e);
}
__device__ __forceinline__ __half2 silu_h2(__half2 x, __half2 kf, __half2 one2) {
    __half2 e = h2exp2(__hmul2(x, kf));
    return __hmul2(x, h2rcp(__hadd2(one2, e)));
}

struct Ptrs { const void* p[14]; };
// p: 0 pos, 1 embed, 2 ew1, 3 eb1, 4 ew2, 5 eb2, 6 nw1, 7 nb1, 8 nw2,
//    9 nb2, 10 lng, 11 lnb, 12 ow, 13 ob

__device__ __forceinline__ float ldf(const void* p, int i, int bf) {
    return bf ? bf2f(((const unsigned short*)p)[i]) : ((const float*)p)[i];
}

// small canon (fp32) offsets: pos 0(12288) embed 12288(1280) wd 13568(512)
// eb1 14080 eb2 14592 nb1 15104 nb2 15616 lng 16128 lnb 16640 (512 each)
// ow 17152(384) ob 17536(3). total 17539.
#define ELEM_TOTAL 393216
#define SMALL_TOTAL 17539

// Swizzle weights into f16 B-fragment order for mfma_f32_16x16x32_f16.
// dst[f*8+j] = W[rowoff + s*32 + ((l>>4)<<3) + j][c*16 + (l&15)], f=(s*8+c)*64+l.
// Per-layer frag bases (f16 elems): wa 0, wb 16384, ew2 32768, nw1 49152,
// nw2 81920; layer stride 98304.
__global__ __launch_bounds__(256) void prep_kernel(
    Ptrs ptrs, f16* dst, float* sc)
{
    __shared__ int flgsh;
    int t = threadIdx.x;
    if (t < 64) {
        int ex = (((const unsigned short*)ptrs.p[0])[t * 2] >> 7) & 0xFF;
        unsigned long long m = __ballot(ex >= 110 && ex <= 135);
        if (t == 0) flgsh = (__popcll(m) >= 40) ? 1 : 0;
    }
    __syncthreads();
    int bf = flgsh;

    int gid = blockIdx.x * 256 + t;
    if (gid < ELEM_TOTAL) {
        int f = gid >> 3, j = gid & 7;
        int lay = f / 12288;
        int r   = f % 12288;
        const void* src; int base, rowoff = 0, r2;
        if (r < 6144) {
            int mat = r >> 11; r2 = r & 2047;
            if (mat == 0)      { src = ptrs.p[2]; base = lay * 32896; }
            else if (mat == 1) { src = ptrs.p[2]; base = lay * 32896; rowoff = 128; }
            else               { src = ptrs.p[4]; base = lay * 16384; }
        } else if (r < 10240) {
            r2 = r - 6144; src = ptrs.p[6]; base = lay * 32768;
        } else {
            r2 = r - 10240; src = ptrs.p[8]; base = lay * 16384;
        }
        int s = r2 >> 9, c = (r2 >> 6) & 7, l = r2 & 63;
        int row = rowoff + s * 32 + ((l >> 4) << 3) + j;
        int col = (c << 4) + (l & 15);
        dst[gid] = (f16)ldf(src, base + row * 128 + col, bf);
    } else {
        int sid = gid - ELEM_TOTAL;
        if (sid >= SMALL_TOTAL) return;
        const void* src; int i;
        if      (sid < 12288) { src = ptrs.p[0]; i = sid; }
        else if (sid < 13568) { src = ptrs.p[1]; i = sid - 12288; }
        else if (sid < 14080) { int k = sid - 13568;
                                src = ptrs.p[2]; i = (k >> 7) * 32896 + 32768 + (k & 127); }
        else if (sid < 14592) { src = ptrs.p[3];  i = sid - 14080; }
        else if (sid < 15104) { src = ptrs.p[5];  i = sid - 14592; }
        else if (sid < 15616) { src = ptrs.p[7];  i = sid - 15104; }
        else if (sid < 16128) { src = ptrs.p[9];  i = sid - 15616; }
        else if (sid < 16640) { src = ptrs.p[10]; i = sid - 16128; }
        else if (sid < 17152) { src = ptrs.p[11]; i = sid - 16640; }
        else if (sid < 17536) { src = ptrs.p[12]; i = sid - 17152; }
        else                  { src = ptrs.p[13]; i = sid - 17536; }
        sc[sid] = ldf(src, i, bf);
    }
}

// h = embed[an]; a = h@wa + eb1; b = h@wb. (r13-proven, 512 thr, c = w)
__global__ __launch_bounds__(512) void embed_ab_kernel(
    const int* an, const float* sc, const f16* wa, const f16* wb,
    const float* eb1C, f16* h16, f16* a16, f16* b16)
{
    int t = threadIdx.x;
    int w = t >> 6, lane = t & 63;
    int row0 = blockIdx.x << 4;
    int m_ = lane & 15, q_ = lane >> 4;
    const float* emb = sc + 12288;
    int a = an[row0 + m_];
    a = a < 0 ? 0 : (a > 9 ? 9 : a);
    f16x8 afrag[4];
#pragma unroll
    for (int s = 0; s < 4; s++) {
        f32x4 u0 = *(const f32x4*)(emb + a * 128 + s * 32 + q_ * 8);
        f32x4 u1 = *(const f32x4*)(emb + a * 128 + s * 32 + q_ * 8 + 4);
        f16x8 hv;
#pragma unroll
        for (int e = 0; e < 4; e++) { hv[e] = (f16)u0[e]; hv[e + 4] = (f16)u1[e]; }
        afrag[s] = hv;
        if (w == 0)
            *(f16x8*)(h16 + (row0 + m_) * 128 + s * 32 + q_ * 8) = hv;
    }
    int c = w;
#pragma unroll
    for (int mat = 0; mat < 2; mat++) {
        const f16* W = mat ? wb : wa;
        f16* out     = mat ? b16 : a16;
        float init = mat ? 0.0f : eb1C[c * 16 + m_];
        f32x4 acc = { init, init, init, init };
#pragma unroll
        for (int s = 0; s < 4; s++) {
            f16x8 bfr = *(const f16x8*)(W + ((s * 8 + c) * 64 + lane) * 8);
            acc = __builtin_amdgcn_mfma_f32_16x16x32_f16(afrag[s], bfr, acc, 0, 0, 0);
        }
#pragma unroll
        for (int r = 0; r < 4; r++)
            out[(row0 + q_ * 4 + r) * 128 + c * 16 + m_] = (f16)acc[r];
    }
}

// Fused edge+node for one layer. Block = (batch b, part): rows r0..r0+7.
// 1024 threads = 16 waves; 2 blocks/CU -> 32 waves/CU (VGPR forced <= 64).
// EDGE: wave w owns i = w>>1, cc-half ccb = (w&1)*4. Per mb: build sf[4]
// S-fragments (packed silu); per cc' in half: 4 slab reads + 4 MFMA + scalar
// silu + msum; sched_barrier(0) bounds in-flight regs. NODE: waves 0-7 only
// (r19 structure, m8 row duplication); af2 split into two 4-frag passes.
__global__ __launch_bounds__(1024, 8) void layer_kernel(
    const void* pos_raw, const float* sc, const f16* Wswz, int lay,
    f16* h16, f16* a16, const f16* bcur, f16* bnxt, void* out)
{
    __shared__ f16 ew2sl[16384];        // 32 KB swizzled ew2
    __shared__ f16 b_lds[64 * 136];     // 17 KB
    __shared__ f16 ar_lds[8 * 136];     // a rows (edge) -> relay (node)
    __shared__ f16 m_lds[8 * 136];
    __shared__ __half dsqh[512];        // [i<8][j]
    __shared__ f16 wd16[128];
    __shared__ float s1sh[8][16], s2sh[8][16];
    __shared__ float psh[8][16][3];
    __shared__ int flgsh;

    int t = threadIdx.x;
    int w = t >> 6, lane = t & 63;
    int m_ = lane & 15, q_ = lane >> 4;
    int m8 = m_ & 7;
    int b  = blockIdx.x >> 3;
    int r0 = b * 64 + (blockIdx.x & 7) * 8;
    const int fin = (lay == 3);

    const f16* wl   = Wswz + lay * 98304;
    const f16* ew2s = wl + 32768;
    const f16* nw1s = wl + 49152;
    const f16* nw2s = wl + 81920;
    const float* posC = sc;
    const float* wdC  = sc + 13568 + lay * 128;
    const float* eb2C = sc + 14592 + lay * 128;
    const float* nb1C = sc + 15104 + lay * 128;
    const float* nb2C = sc + 15616 + lay * 128;
    const float* lngC = sc + 16128 + lay * 128;
    const float* lnbC = sc + 16640 + lay * 128;

    if (t < 64) {
        int ex = (((const unsigned short*)pos_raw)[t * 2] >> 7) & 0xFF;
        unsigned long long mk = __ballot(ex >= 110 && ex <= 135);
        if (t == 0) flgsh = (__popcll(mk) >= 40) ? 1 : 0;
    }

    // ---- stage: ew2 slab, b tile, a rows, dsq, wd ----
#pragma unroll
    for (int k = 0; k < 2; k++) {
        int idx = (k * 1024 + t) * 8;
        *(f16x8*)(ew2sl + idx) = *(const f16x8*)(ew2s + idx);
    }
    {
        int j = t >> 4, col0 = (t & 15) * 8;
        *(f16x8*)(b_lds + j * 136 + col0) =
            *(const f16x8*)(bcur + (b * 64 + j) * 128 + col0);
    }
    if (t < 128) {
        int row = t >> 4, col0 = (t & 15) * 8;
        *(f16x8*)(ar_lds + row * 136 + col0) =
            *(const f16x8*)(a16 + (r0 + row) * 128 + col0);
    }
    if (t < 512) {
        int i = t >> 6, j = t & 63;
        int gi = r0 + i, gj = b * 64 + j;
        float dx = posC[gi * 3 + 0] - posC[gj * 3 + 0];
        float dy = posC[gi * 3 + 1] - posC[gj * 3 + 1];
        float dz = posC[gi * 3 + 2] - posC[gj * 3 + 2];
        dsqh[t] = __float2half_rn(dx * dx + dy * dy + dz * dz);
    }
    if (t >= 512 && t < 640) wd16[t - 512] = (f16)wdC[t - 512];
    __syncthreads();

    // ---- edge: wave w owns i = w>>1, cc-half ccb = (w&1)*4 ----
    {
        int i   = w >> 1;
        int ccb = (w & 1) * 4;
        float eb2v[4];
#pragma unroll
        for (int cc = 0; cc < 4; cc++) eb2v[cc] = eb2C[(ccb + cc) * 16 + m_];
        const __half2 kf   = __floats2half2_rn(-1.44269504f, -1.44269504f);
        const __half2 one2 = __floats2half2_rn(1.0f, 1.0f);
        float msum[4] = { 0.f, 0.f, 0.f, 0.f };
#pragma unroll 1
        for (int mb = 0; mb < 4; mb++) {
            int j = mb * 16 + m_;
            __half dh = dsqh[i * 64 + j];
            __half2 ds2 = __halves2half2(dh, dh);
            f16x8 sf[4];
#pragma unroll
            for (int s = 0; s < 4; s++) {
                H2x4 av_, bv, wv, sv;
                av_.v = *(const f16x8*)(ar_lds + i * 136 + s * 32 + q_ * 8);
                bv.v  = *(const f16x8*)(b_lds + j * 136 + s * 32 + q_ * 8);
                wv.v  = *(const f16x8*)(wd16 + s * 32 + q_ * 8);
#pragma unroll
                for (int e = 0; e < 4; e++) {
                    __half2 pre = __hfma2(ds2, wv.h[e],
                                          __hadd2(av_.h[e], bv.h[e]));
                    sv.h[e] = silu_h2(pre, kf, one2);
                }
                sf[s] = sv.v;
            }
#pragma unroll
            for (int cc = 0; cc < 4; cc++) {
                f32x4 acc = { eb2v[cc], eb2v[cc], eb2v[cc], eb2v[cc] };
#pragma unroll
                for (int s = 0; s < 4; s++) {
                    f16x8 wf = *(const f16x8*)(ew2sl +
                        ((s * 8 + ccb + cc) * 64 + lane) * 8);
                    acc = __builtin_amdgcn_mfma_f32_16x16x32_f16(sf[s], wf, acc, 0, 0, 0);
                }
                msum[cc] += silu_f(acc[0]) + silu_f(acc[1])
                          + silu_f(acc[2]) + silu_f(acc[3]);
                __builtin_amdgcn_sched_barrier(0);   // bound reg pressure
            }
        }
#pragma unroll
        for (int cc = 0; cc < 4; cc++) {
            float red = msum[cc];
            red += __shfl_xor(red, 16);
            red += __shfl_xor(red, 32);
            if (lane < 16)
                m_lds[i * 136 + (ccb + cc) * 16 + lane] = (f16)(red * 0.015625f);
        }
    }
    __syncthreads();   // m_lds ready; ar_lds free for relay reuse

    // ---- node (waves 0-7 only; 8-row block, m8 duplication) ----
    f16* relay = ar_lds;
    int c = w;                           // col tile for w<8
    if (w < 8) {
        float e = nb1C[c * 16 + m_];
        f32x4 acc = { e, e, e, e };
#pragma unroll
        for (int s = 0; s < 4; s++) {
            f16x8 af = *(const f16x8*)(h16 + (r0 + m8) * 128 + s * 32 + q_ * 8);
            f16x8 bv = *(const f16x8*)(nw1s + ((s * 8 + c) * 64 + lane) * 8);
            acc = __builtin_amdgcn_mfma_f32_16x16x32_f16(af, bv, acc, 0, 0, 0);
        }
#pragma unroll
        for (int s = 0; s < 4; s++) {
            f16x8 af = *(const f16x8*)(m_lds + m8 * 136 + s * 32 + q_ * 8);
            f16x8 bv = *(const f16x8*)(nw1s + (((s + 4) * 8 + c) * 64 + lane) * 8);
            acc = __builtin_amdgcn_mfma_f32_16x16x32_f16(af, bv, acc, 0, 0, 0);
        }
        if (q_ < 2)
#pragma unroll
            for (int r = 0; r < 4; r++)
                relay[(q_ * 4 + r) * 136 + c * 16 + m_] = (f16)silu_f(acc[r]);
    }
    __syncthreads();
    float x[4], mu[4], rs[4];
    if (w < 8) {
        float e = nb2C[c * 16 + m_];
        f32x4 acc = { e, e, e, e };
#pragma unroll
        for (int s = 0; s < 4; s++) {
            f16x8 uf = *(const f16x8*)(relay + m8 * 136 + s * 32 + q_ * 8);
            f16x8 bv = *(const f16x8*)(nw2s + ((s * 8 + c) * 64 + lane) * 8);
            acc = __builtin_amdgcn_mfma_f32_16x16x32_f16(uf, bv, acc, 0, 0, 0);
        }
#pragma unroll
        for (int r = 0; r < 4; r++) {
            int row = q_ * 4 + r;
            x[r] = acc[r] + (float)h16[(r0 + (row & 7)) * 128 + c * 16 + m_];
        }
        float s1p[4], s2p[4];
#pragma unroll
        for (int r = 0; r < 4; r++) { s1p[r] = x[r]; s2p[r] = x[r] * x[r]; }
#pragma unroll
        for (int msk = 1; msk < 16; msk <<= 1)
#pragma unroll
            for (int r = 0; r < 4; r++) {
                s1p[r] += __shfl_xor(s1p[r], msk);
                s2p[r] += __shfl_xor(s2p[r], msk);
            }
        if (m_ == 0)
#pragma unroll
            for (int r = 0; r < 4; r++) {
                s1sh[w][q_ * 4 + r] = s1p[r];
                s2sh[w][q_ * 4 + r] = s2p[r];
            }
    }
    __syncthreads();
    if (w < 8) {
#pragma unroll
        for (int r = 0; r < 4; r++) {
            int row = (q_ * 4 + r) & 7;   // rows>=8 mirror 0..7
            float S1 = 0.f, S2 = 0.f;
#pragma unroll
            for (int w2 = 0; w2 < 8; w2++) { S1 += s1sh[w2][row]; S2 += s2sh[w2][row]; }
            mu[r] = S1 * (1.0f / 128.0f);
            float var = S2 * (1.0f / 128.0f) - mu[r] * mu[r];
            rs[r] = rsqrtf(var + 1e-5f);
        }
    }

    if (!fin) {
        if (w < 8 && q_ < 2)
#pragma unroll
            for (int r = 0; r < 4; r++) {
                int col = c * 16 + m_;
                int row = r0 + q_ * 4 + r;
                float y = (x[r] - mu[r]) * rs[r] * lngC[col] + lnbC[col];
                h16[row * 128 + col] = (f16)y;
                relay[(q_ * 4 + r) * 136 + col] = (f16)y;
            }
        __syncthreads();
        if (w < 8) {
            const f16* wlN = Wswz + (lay + 1) * 98304;
            const float* eb1N = sc + 14080 + (lay + 1) * 128;
#pragma unroll
            for (int mat = 0; mat < 2; mat++) {
                const f16* W = mat ? (wlN + 16384) : wlN;
                float init = mat ? 0.0f : eb1N[c * 16 + m_];
                f32x4 acc = { init, init, init, init };
#pragma unroll
                for (int s = 0; s < 4; s++) {
                    f16x8 hf = *(const f16x8*)(relay + m8 * 136 + s * 32 + q_ * 8);
                    f16x8 bv = *(const f16x8*)(W + ((s * 8 + c) * 64 + lane) * 8);
                    acc = __builtin_amdgcn_mfma_f32_16x16x32_f16(hf, bv, acc, 0, 0, 0);
                }
                if (q_ < 2)
#pragma unroll
                    for (int r = 0; r < 4; r++) {
                        if (mat == 0)
                            a16[(r0 + q_ * 4 + r) * 128 + c * 16 + m_] = (f16)acc[r];
                        else
                            bnxt[(r0 + q_ * 4 + r) * 128 + c * 16 + m_] = (f16)acc[r];
                    }
            }
        }
    } else {
        if (w < 8) {
            const float* owC = sc + 17152;
            float p[3][4];
#pragma unroll
            for (int r = 0; r < 4; r++) {
                int col = c * 16 + m_;
                float y = (x[r] - mu[r]) * rs[r] * lngC[col] + lnbC[col];
                p[0][r] = y * owC[col * 3 + 0];
                p[1][r] = y * owC[col * 3 + 1];
                p[2][r] = y * owC[col * 3 + 2];
            }
#pragma unroll
            for (int msk = 1; msk < 16; msk <<= 1)
#pragma unroll
                for (int k = 0; k < 3; k++)
#pragma unroll
                    for (int r = 0; r < 4; r++)
                        p[k][r] += __shfl_xor(p[k][r], msk);
            if (m_ == 0)
#pragma unroll
                for (int r = 0; r < 4; r++)
#pragma unroll
                    for (int k = 0; k < 3; k++)
                        psh[w][q_ * 4 + r][k] = p[k][r];
        }
        __syncthreads();
        if (t < 8) {
            const float* obC = sc + 17536;
            int row = r0 + t;
            int bf = flgsh;
#pragma unroll
            for (int k = 0; k < 3; k++) {
                float v = obC[k];
#pragma unroll
                for (int w2 = 0; w2 < 8; w2++) v += psh[w2][t][k];
                if (bf) ((unsigned short*)out)[row * 3 + k] = f2bf(v);
                else    ((float*)out)[row * 3 + k] = v;
            }
        }
    }
}

extern "C" void kernel_launch(void* const* d_in, const int* in_sizes, int n_in,
                              void* d_out, int out_size, void* d_ws, size_t ws_size,
                              hipStream_t stream)
{
    char* ws = (char*)d_ws;
    float* sc   = (float*)(ws + 1024);              // 70 KB
    f16*   Wswz = (f16*)(ws + (128u << 10));        // 768 KB
    f16*   h16  = (f16*)(ws + (1u << 20));
    f16*   a16  = (f16*)(ws + (2u << 20));
    f16*   b0   = (f16*)(ws + (3u << 20));
    f16*   b1   = (f16*)(ws + (4u << 20));          // total 5 MB

    Ptrs ptrs;
    const int src_idx[14] = {0, 2, 3, 4, 5, 6, 7, 8, 9, 10, 11, 12, 13, 14};
    for (int k = 0; k < 14; k++) ptrs.p[k] = d_in[src_idx[k]];

    prep_kernel<<<1605, 256, 0, stream>>>(ptrs, Wswz, sc);
    embed_ab_kernel<<<256, 512, 0, stream>>>((const int*)d_in[1], sc, Wswz,
                                             Wswz + 16384, sc + 14080,
                                             h16, a16, b0);
    for (int lay = 0; lay < 4; lay++) {
        const f16* bcur = (lay & 1) ? b1 : b0;
        f16*       bnxt = (lay & 1) ? b0 : b1;
        layer_kernel<<<512, 1024, 0, stream>>>(d_in[0], sc, Wswz, lay,
                                               h16, a16, bcur, bnxt, d_out);
    }
}

// Round 11
// 203.165 us; speedup vs baseline: 1.1598x; 1.1598x over previous
//
#include <hip/hip_runtime.h>
#include <hip/hip_fp16.h>

// B=64, N=64, D=128, L=4, T=10. Float tensors may arrive as bf16 OR fp32.
// r22: r19 skeleton VERBATIM (proven best, 203.3us) + one change: packed
// half2 post-GEMM silu (256 -> 128 trans instrs/wave in the edge loop).
// Ledger: r13/r16 38.5us/layer, r17 106 (spill), r18 38.5, r19 36 (best),
// r20b 47 (cc-outer reorder hurt), r21 44 (forced launch-bounds spill,
// VGPR=32, WRITE 20MB). Occupancy is falsified both ways (r19 2x occ -> +5us;
// r21 55% occ -> worse). Only lever left: fewer per-wave instructions at
// unchanged structure/order/registers. r20b proved packed-silu math correct.

typedef _Float16 f16;
typedef _Float16 f16x8 __attribute__((ext_vector_type(8)));
typedef float f32x4 __attribute__((ext_vector_type(4)));

union H2x4 { f16x8 v; __half2 h[4]; };

__device__ __forceinline__ float bf2f(unsigned short u) {
    union { unsigned int i; float f; } v; v.i = ((unsigned int)u) << 16; return v.f;
}
__device__ __forceinline__ unsigned short f2bf(float f) {
    union { float f; unsigned int i; } v; v.f = f;
    unsigned int x = v.i;
    return (unsigned short)((x + 0x7fffu + ((x >> 16) & 1u)) >> 16);
}
__device__ __forceinline__ float silu_f(float x) {
    float e = __builtin_amdgcn_exp2f(-1.44269504088896f * x);
    return x * __builtin_amdgcn_rcpf(1.0f + e);
}
__device__ __forceinline__ __half2 silu_h2(__half2 x, __half2 kf, __half2 one2) {
    __half2 e = h2exp2(__hmul2(x, kf));
    return __hmul2(x, h2rcp(__hadd2(one2, e)));
}
__device__ __forceinline__ __half2 pk_h2(float a, float b) {
    auto p = __builtin_amdgcn_cvt_pkrtz(a, b);   // __fp16 ext_vector(2)
    __half2 r;
    __builtin_memcpy(&r, &p, sizeof(r));
    return r;
}

struct Ptrs { const void* p[14]; };
// p: 0 pos, 1 embed, 2 ew1, 3 eb1, 4 ew2, 5 eb2, 6 nw1, 7 nb1, 8 nw2,
//    9 nb2, 10 lng, 11 lnb, 12 ow, 13 ob

__device__ __forceinline__ float ldf(const void* p, int i, int bf) {
    return bf ? bf2f(((const unsigned short*)p)[i]) : ((const float*)p)[i];
}

// small canon (fp32) offsets: pos 0(12288) embed 12288(1280) wd 13568(512)
// eb1 14080 eb2 14592 nb1 15104 nb2 15616 lng 16128 lnb 16640 (512 each)
// ow 17152(384) ob 17536(3). total 17539.
#define ELEM_TOTAL 393216
#define SMALL_TOTAL 17539

// Swizzle weights into f16 B-fragment order for mfma_f32_16x16x32_f16.
// dst[f*8+j] = W[rowoff + s*32 + ((l>>4)<<3) + j][c*16 + (l&15)], f=(s*8+c)*64+l.
// Per-layer frag bases (f16 elems): wa 0, wb 16384, ew2 32768, nw1 49152,
// nw2 81920; layer stride 98304.
__global__ __launch_bounds__(256) void prep_kernel(
    Ptrs ptrs, f16* dst, float* sc)
{
    __shared__ int flgsh;
    int t = threadIdx.x;
    if (t < 64) {
        int ex = (((const unsigned short*)ptrs.p[0])[t * 2] >> 7) & 0xFF;
        unsigned long long m = __ballot(ex >= 110 && ex <= 135);
        if (t == 0) flgsh = (__popcll(m) >= 40) ? 1 : 0;
    }
    __syncthreads();
    int bf = flgsh;

    int gid = blockIdx.x * 256 + t;
    if (gid < ELEM_TOTAL) {
        int f = gid >> 3, j = gid & 7;
        int lay = f / 12288;
        int r   = f % 12288;
        const void* src; int base, rowoff = 0, r2;
        if (r < 6144) {
            int mat = r >> 11; r2 = r & 2047;
            if (mat == 0)      { src = ptrs.p[2]; base = lay * 32896; }
            else if (mat == 1) { src = ptrs.p[2]; base = lay * 32896; rowoff = 128; }
            else               { src = ptrs.p[4]; base = lay * 16384; }
        } else if (r < 10240) {
            r2 = r - 6144; src = ptrs.p[6]; base = lay * 32768;
        } else {
            r2 = r - 10240; src = ptrs.p[8]; base = lay * 16384;
        }
        int s = r2 >> 9, c = (r2 >> 6) & 7, l = r2 & 63;
        int row = rowoff + s * 32 + ((l >> 4) << 3) + j;
        int col = (c << 4) + (l & 15);
        dst[gid] = (f16)ldf(src, base + row * 128 + col, bf);
    } else {
        int sid = gid - ELEM_TOTAL;
        if (sid >= SMALL_TOTAL) return;
        const void* src; int i;
        if      (sid < 12288) { src = ptrs.p[0]; i = sid; }
        else if (sid < 13568) { src = ptrs.p[1]; i = sid - 12288; }
        else if (sid < 14080) { int k = sid - 13568;
                                src = ptrs.p[2]; i = (k >> 7) * 32896 + 32768 + (k & 127); }
        else if (sid < 14592) { src = ptrs.p[3];  i = sid - 14080; }
        else if (sid < 15104) { src = ptrs.p[5];  i = sid - 14592; }
        else if (sid < 15616) { src = ptrs.p[7];  i = sid - 15104; }
        else if (sid < 16128) { src = ptrs.p[9];  i = sid - 15616; }
        else if (sid < 16640) { src = ptrs.p[10]; i = sid - 16128; }
        else if (sid < 17152) { src = ptrs.p[11]; i = sid - 16640; }
        else if (sid < 17536) { src = ptrs.p[12]; i = sid - 17152; }
        else                  { src = ptrs.p[13]; i = sid - 17536; }
        sc[sid] = ldf(src, i, bf);
    }
}

// h = embed[an]; a = h@wa + eb1; b = h@wb. (r13-proven, 512 thr, c = w)
__global__ __launch_bounds__(512) void embed_ab_kernel(
    const int* an, const float* sc, const f16* wa, const f16* wb,
    const float* eb1C, f16* h16, f16* a16, f16* b16)
{
    int t = threadIdx.x;
    int w = t >> 6, lane = t & 63;
    int row0 = blockIdx.x << 4;
    int m_ = lane & 15, q_ = lane >> 4;
    const float* emb = sc + 12288;
    int a = an[row0 + m_];
    a = a < 0 ? 0 : (a > 9 ? 9 : a);
    f16x8 afrag[4];
#pragma unroll
    for (int s = 0; s < 4; s++) {
        f32x4 u0 = *(const f32x4*)(emb + a * 128 + s * 32 + q_ * 8);
        f32x4 u1 = *(const f32x4*)(emb + a * 128 + s * 32 + q_ * 8 + 4);
        f16x8 hv;
#pragma unroll
        for (int e = 0; e < 4; e++) { hv[e] = (f16)u0[e]; hv[e + 4] = (f16)u1[e]; }
        afrag[s] = hv;
        if (w == 0)
            *(f16x8*)(h16 + (row0 + m_) * 128 + s * 32 + q_ * 8) = hv;
    }
    int c = w;
#pragma unroll
    for (int mat = 0; mat < 2; mat++) {
        const f16* W = mat ? wb : wa;
        f16* out     = mat ? b16 : a16;
        float init = mat ? 0.0f : eb1C[c * 16 + m_];
        f32x4 acc = { init, init, init, init };
#pragma unroll
        for (int s = 0; s < 4; s++) {
            f16x8 bfr = *(const f16x8*)(W + ((s * 8 + c) * 64 + lane) * 8);
            acc = __builtin_amdgcn_mfma_f32_16x16x32_f16(afrag[s], bfr, acc, 0, 0, 0);
        }
#pragma unroll
        for (int r = 0; r < 4; r++)
            out[(row0 + q_ * 4 + r) * 128 + c * 16 + m_] = (f16)acc[r];
    }
}

// Fused edge+node for one layer. Block = (batch b, part): rows r0..r0+7.
// 512 threads, 8 waves, 2 blocks/CU.
// EDGE (barrier-free): wave w owns row i = w; per (i, mb) the 16x128 S-tile
// is built in MFMA A-fragment registers; per cc: one 4-MFMA acc chain,
// PACKED half2 post-silu (r22), sched_barrier(0) between cc blocks.
// NODE: r19 structure (8-row blocks, m8 duplication).
__global__ __launch_bounds__(512) void layer_kernel(
    const void* pos_raw, const float* sc, const f16* Wswz, int lay,
    f16* h16, f16* a16, const f16* bcur, f16* bnxt, void* out)
{
    __shared__ f16 ew2sl[16384];        // 32 KB swizzled ew2
    __shared__ f16 b_lds[64 * 136];     // 17 KB
    __shared__ f16 ar_lds[8 * 136];     // a rows (edge) -> relay (node)
    __shared__ f16 m_lds[8 * 136];
    __shared__ __half dsqh[512];        // [i<8][j]
    __shared__ f16 wd16[128];
    __shared__ float s1sh[8][16], s2sh[8][16];
    __shared__ float psh[8][16][3];
    __shared__ int flgsh;

    int t = threadIdx.x;
    int w = t >> 6, lane = t & 63;
    int m_ = lane & 15, q_ = lane >> 4;
    int m8 = m_ & 7;
    int c = w;
    int b  = blockIdx.x >> 3;
    int r0 = b * 64 + (blockIdx.x & 7) * 8;
    const int fin = (lay == 3);

    const f16* wl   = Wswz + lay * 98304;
    const f16* ew2s = wl + 32768;
    const f16* nw1s = wl + 49152;
    const f16* nw2s = wl + 81920;
    const float* posC = sc;
    const float* wdC  = sc + 13568 + lay * 128;
    const float* eb2C = sc + 14592 + lay * 128;
    const float* nb1C = sc + 15104 + lay * 128;
    const float* nb2C = sc + 15616 + lay * 128;
    const float* lngC = sc + 16128 + lay * 128;
    const float* lnbC = sc + 16640 + lay * 128;

    if (t < 64) {
        int ex = (((const unsigned short*)pos_raw)[t * 2] >> 7) & 0xFF;
        unsigned long long mk = __ballot(ex >= 110 && ex <= 135);
        if (t == 0) flgsh = (__popcll(mk) >= 40) ? 1 : 0;
    }

    // ---- stage: ew2 slab, b tile, a rows, dsq, wd ----
#pragma unroll
    for (int k = 0; k < 4; k++) {
        int idx = (k * 512 + t) * 8;
        *(f16x8*)(ew2sl + idx) = *(const f16x8*)(ew2s + idx);
    }
#pragma unroll
    for (int kk = 0; kk < 2; kk++) {
        int k = t + 512 * kk;
        int j = k >> 4, col0 = (k & 15) * 8;
        *(f16x8*)(b_lds + j * 136 + col0) =
            *(const f16x8*)(bcur + (b * 64 + j) * 128 + col0);
    }
    if (t < 128) {
        int row = t >> 4, col0 = (t & 15) * 8;
        *(f16x8*)(ar_lds + row * 136 + col0) =
            *(const f16x8*)(a16 + (r0 + row) * 128 + col0);
    }
    {
        int i = t >> 6, j = t & 63;
        int gi = r0 + i, gj = b * 64 + j;
        float dx = posC[gi * 3 + 0] - posC[gj * 3 + 0];
        float dy = posC[gi * 3 + 1] - posC[gj * 3 + 1];
        float dz = posC[gi * 3 + 2] - posC[gj * 3 + 2];
        dsqh[t] = __float2half_rn(dx * dx + dy * dy + dz * dz);
    }
    if (t < 128) wd16[t] = (f16)wdC[t];
    __syncthreads();

    // ---- edge: barrier-free; wave w owns row i = w ----
    {
        int i = w;
        f16x8 wdf[4];
#pragma unroll
        for (int s = 0; s < 4; s++)
            wdf[s] = *(const f16x8*)(wd16 + s * 32 + q_ * 8);
        float eb2v[8];
#pragma unroll
        for (int cc = 0; cc < 8; cc++) eb2v[cc] = eb2C[cc * 16 + m_];
        const __half2 kf   = __floats2half2_rn(-1.44269504f, -1.44269504f);
        const __half2 one2 = __floats2half2_rn(1.0f, 1.0f);
        f16x8 av[4];
#pragma unroll
        for (int s = 0; s < 4; s++)
            av[s] = *(const f16x8*)(ar_lds + i * 136 + s * 32 + q_ * 8);
        float msum[8] = { 0.f, 0.f, 0.f, 0.f, 0.f, 0.f, 0.f, 0.f };
#pragma unroll 1
        for (int mb = 0; mb < 4; mb++) {
            int j = mb * 16 + m_;
            __half dh = dsqh[i * 64 + j];
            __half2 ds2 = __halves2half2(dh, dh);
            f16x8 sf[4];
#pragma unroll
            for (int s = 0; s < 4; s++) {
                H2x4 av_, bv, wv, sv;
                av_.v = av[s];
                bv.v = *(const f16x8*)(b_lds + j * 136 + s * 32 + q_ * 8);
                wv.v = wdf[s];
#pragma unroll
                for (int e = 0; e < 4; e++) {
                    __half2 pre = __hfma2(ds2, wv.h[e],
                                          __hadd2(av_.h[e], bv.h[e]));
                    sv.h[e] = silu_h2(pre, kf, one2);
                }
                sf[s] = sv.v;
            }
#pragma unroll
            for (int cc = 0; cc < 8; cc++) {
                f32x4 acc = { eb2v[cc], eb2v[cc], eb2v[cc], eb2v[cc] };
#pragma unroll
                for (int s = 0; s < 4; s++) {
                    f16x8 wf = *(const f16x8*)(ew2sl + ((s * 8 + cc) * 64 + lane) * 8);
                    acc = __builtin_amdgcn_mfma_f32_16x16x32_f16(sf[s], wf, acc, 0, 0, 0);
                }
                // r22: packed post-silu (was 4x scalar silu_f)
                __half2 t2 = __hadd2(silu_h2(pk_h2(acc[0], acc[1]), kf, one2),
                                     silu_h2(pk_h2(acc[2], acc[3]), kf, one2));
                msum[cc] += __low2float(t2) + __high2float(t2);
                __builtin_amdgcn_sched_barrier(0);   // bound reg pressure
            }
        }
#pragma unroll
        for (int cc = 0; cc < 8; cc++) {
            float red = msum[cc];
            red += __shfl_xor(red, 16);
            red += __shfl_xor(red, 32);
            if (lane < 16)
                m_lds[i * 136 + cc * 16 + lane] = (f16)(red * 0.015625f);
        }
    }
    __syncthreads();   // m_lds ready; ar_lds free for relay reuse

    // ---- node (8-row block: A rows duplicated via m8; writes row<8) ----
    f16x8 af2[8];
#pragma unroll
    for (int s = 0; s < 4; s++) {
        af2[s]     = *(const f16x8*)(h16 + (r0 + m8) * 128 + s * 32 + q_ * 8);
        af2[s + 4] = *(const f16x8*)(m_lds + m8 * 136 + s * 32 + q_ * 8);
    }
    f16* relay = ar_lds;
    {
        float e = nb1C[c * 16 + m_];
        f32x4 acc = { e, e, e, e };
#pragma unroll
        for (int s = 0; s < 8; s++) {
            f16x8 bv = *(const f16x8*)(nw1s + ((s * 8 + c) * 64 + lane) * 8);
            acc = __builtin_amdgcn_mfma_f32_16x16x32_f16(af2[s], bv, acc, 0, 0, 0);
        }
        if (q_ < 2)
#pragma unroll
            for (int r = 0; r < 4; r++)
                relay[(q_ * 4 + r) * 136 + c * 16 + m_] = (f16)silu_f(acc[r]);
    }
    __syncthreads();
    f16x8 uf[4];
#pragma unroll
    for (int s = 0; s < 4; s++)
        uf[s] = *(const f16x8*)(relay + m8 * 136 + s * 32 + q_ * 8);
    float x[4];
    {
        float e = nb2C[c * 16 + m_];
        f32x4 acc = { e, e, e, e };
#pragma unroll
        for (int s = 0; s < 4; s++) {
            f16x8 bv = *(const f16x8*)(nw2s + ((s * 8 + c) * 64 + lane) * 8);
            acc = __builtin_amdgcn_mfma_f32_16x16x32_f16(uf[s], bv, acc, 0, 0, 0);
        }
#pragma unroll
        for (int r = 0; r < 4; r++) {
            int row = q_ * 4 + r;
            // rows >= 8 are duplicates; their h16 read is clamped in-range
            x[r] = acc[r] + (float)h16[(r0 + (row & 7)) * 128 + c * 16 + m_];
        }
    }
    float s1p[4], s2p[4];
#pragma unroll
    for (int r = 0; r < 4; r++) { s1p[r] = x[r]; s2p[r] = x[r] * x[r]; }
#pragma unroll
    for (int msk = 1; msk < 16; msk <<= 1)
#pragma unroll
        for (int r = 0; r < 4; r++) {
            s1p[r] += __shfl_xor(s1p[r], msk);
            s2p[r] += __shfl_xor(s2p[r], msk);
        }
    if (m_ == 0)
#pragma unroll
        for (int r = 0; r < 4; r++) {
            s1sh[w][q_ * 4 + r] = s1p[r];
            s2sh[w][q_ * 4 + r] = s2p[r];
        }
    __syncthreads();
    float mu[4], rs[4];
#pragma unroll
    for (int r = 0; r < 4; r++) {
        int row = (q_ * 4 + r) & 7;   // rows>=8 mirror 0..7
        float S1 = 0.f, S2 = 0.f;
#pragma unroll
        for (int w2 = 0; w2 < 8; w2++) { S1 += s1sh[w2][row]; S2 += s2sh[w2][row]; }
        mu[r] = S1 * (1.0f / 128.0f);
        float var = S2 * (1.0f / 128.0f) - mu[r] * mu[r];
        rs[r] = rsqrtf(var + 1e-5f);
    }

    if (!fin) {
        if (q_ < 2)
#pragma unroll
            for (int r = 0; r < 4; r++) {
                int col = c * 16 + m_;
                int row = r0 + q_ * 4 + r;
                float y = (x[r] - mu[r]) * rs[r] * lngC[col] + lnbC[col];
                h16[row * 128 + col] = (f16)y;
                relay[(q_ * 4 + r) * 136 + col] = (f16)y;
            }
        __syncthreads();
        f16x8 hf[4];
#pragma unroll
        for (int s = 0; s < 4; s++)
            hf[s] = *(const f16x8*)(relay + m8 * 136 + s * 32 + q_ * 8);
        const f16* wlN = Wswz + (lay + 1) * 98304;
        const float* eb1N = sc + 14080 + (lay + 1) * 128;
#pragma unroll
        for (int mat = 0; mat < 2; mat++) {
            const f16* W = mat ? (wlN + 16384) : wlN;
            float init = mat ? 0.0f : eb1N[c * 16 + m_];
            f32x4 acc = { init, init, init, init };
#pragma unroll
            for (int s = 0; s < 4; s++) {
                f16x8 bv = *(const f16x8*)(W + ((s * 8 + c) * 64 + lane) * 8);
                acc = __builtin_amdgcn_mfma_f32_16x16x32_f16(hf[s], bv, acc, 0, 0, 0);
            }
            if (q_ < 2)
#pragma unroll
                for (int r = 0; r < 4; r++) {
                    if (mat == 0)
                        a16[(r0 + q_ * 4 + r) * 128 + c * 16 + m_] = (f16)acc[r];
                    else
                        bnxt[(r0 + q_ * 4 + r) * 128 + c * 16 + m_] = (f16)acc[r];
                }
        }
    } else {
        const float* owC = sc + 17152;
        const float* obC = sc + 17536;
        float p[3][4];
#pragma unroll
        for (int r = 0; r < 4; r++) {
            int col = c * 16 + m_;
            float y = (x[r] - mu[r]) * rs[r] * lngC[col] + lnbC[col];
            p[0][r] = y * owC[col * 3 + 0];
            p[1][r] = y * owC[col * 3 + 1];
            p[2][r] = y * owC[col * 3 + 2];
        }
#pragma unroll
        for (int msk = 1; msk < 16; msk <<= 1)
#pragma unroll
            for (int k = 0; k < 3; k++)
#pragma unroll
                for (int r = 0; r < 4; r++)
                    p[k][r] += __shfl_xor(p[k][r], msk);
        if (m_ == 0)
#pragma unroll
            for (int r = 0; r < 4; r++)
#pragma unroll
                for (int k = 0; k < 3; k++)
                    psh[w][q_ * 4 + r][k] = p[k][r];
        __syncthreads();
        if (t < 8) {
            int row = r0 + t;
            int bf = flgsh;
#pragma unroll
            for (int k = 0; k < 3; k++) {
                float v = obC[k];
#pragma unroll
                for (int w2 = 0; w2 < 8; w2++) v += psh[w2][t][k];
                if (bf) ((unsigned short*)out)[row * 3 + k] = f2bf(v);
                else    ((float*)out)[row * 3 + k] = v;
            }
        }
    }
}

extern "C" void kernel_launch(void* const* d_in, const int* in_sizes, int n_in,
                              void* d_out, int out_size, void* d_ws, size_t ws_size,
                              hipStream_t stream)
{
    char* ws = (char*)d_ws;
    float* sc   = (float*)(ws + 1024);              // 70 KB
    f16*   Wswz = (f16*)(ws + (128u << 10));        // 768 KB
    f16*   h16  = (f16*)(ws + (1u << 20));
    f16*   a16  = (f16*)(ws + (2u << 20));
    f16*   b0   = (f16*)(ws + (3u << 20));
    f16*   b1   = (f16*)(ws + (4u << 20));          // total 5 MB

    Ptrs ptrs;
    const int src_idx[14] = {0, 2, 3, 4, 5, 6, 7, 8, 9, 10, 11, 12, 13, 14};
    for (int k = 0; k < 14; k++) ptrs.p[k] = d_in[src_idx[k]];

    prep_kernel<<<1605, 256, 0, stream>>>(ptrs, Wswz, sc);
    embed_ab_kernel<<<256, 512, 0, stream>>>((const int*)d_in[1], sc, Wswz,
                                             Wswz + 16384, sc + 14080,
                                             h16, a16, b0);
    for (int lay = 0; lay < 4; lay++) {
        const f16* bcur = (lay & 1) ? b1 : b0;
        f16*       bnxt = (lay & 1) ? b0 : b1;
        layer_kernel<<<512, 512, 0, stream>>>(d_in[0], sc, Wswz, lay,
                                              h16, a16, bcur, bnxt, d_out);
    }
}